// Round 8
// baseline (171.301 us; speedup 1.0000x reference)
//
#include <hip/hip_runtime.h>
#include <math.h>

#define NB 8192
#define NC 128
#define NJS 16         // j-slices (grid.y); slice = 512 cols
#define JPT 8          // j-tiles of 64 cols per slice
#define NSL 32         // output slices = NJS * 2 (ch halves)

typedef float v4f __attribute__((ext_vector_type(4)));
typedef int   v8i __attribute__((ext_vector_type(8)));   // 32 fp8 (8 VGPRs)

// R1-R7 lesson ledger (MI355X):
//  - __threadfence (agent) = bulk buffer_wbl2/inv -> tens of us across a grid. NEVER.
//  - grid-wide sync of any flavor: 150+ us. Dispatch boundary for all-to-all.
//  - relaxed-agent atomic ld/st: coherent & cheap for SMALL data (flags, 1KB
//    partials) but BYPASSES caches -> never for bulk operands (R6: +25us).
//  - __syncthreads() drains vmcnt -> write-through stores durable before a
//    post-barrier relaxed RMW: fence-free release (R5-proven).
//  - last-finisher chaining via line-separated counters: cheap (R3/R5-proven).
//  - global_load_lds LDS dest = WAVE-UNIFORM base + lane*16B. Base must step
//    by 256 floats per wave (64 lanes x 16B). R7 bug: used +64 -> overlap+gap
//    in sqs/tjs -> absmax 1e-4. Always reuse the proven `+ w*256` pattern.

// ctl block (128-B lines; word addr = line*32), zeroed by k_prep block 0:
//   line 0       : done counter (128 adds, 0 readers)
//   lines 8..15  : partial sums (line 8+(bx&7): word0=H, word1=CE)
//   lines 16..143: rowcnt[bx]   (16 adds each, 0 readers)

__device__ __forceinline__ float ld_f32(const float* p) {
    return __hip_atomic_load(p, __ATOMIC_RELAXED, __HIP_MEMORY_SCOPE_AGENT);
}
__device__ __forceinline__ void st_f32(float* p, float v) {
    __hip_atomic_store(p, v, __ATOMIC_RELAXED, __HIP_MEMORY_SCOPE_AGENT);
}

// ---------------------------------------------------------------- prep:
// per row: fp8 e4m3 cast (packed 4/lane), sum-of-squares (fp32), CE term
// (fp32). 8 rows per 256-thr block. Block 0 zeroes ctl. (Unchanged R5 code:
// bit-identical xq/sq/ce.)
__global__ __launch_bounds__(256) void k_prep(const float* __restrict__ x,
                                              const int* __restrict__ tgt,
                                              unsigned* __restrict__ xq,   // NB*32 uints
                                              float* __restrict__ sq,
                                              float* __restrict__ ce,
                                              unsigned* __restrict__ ctl) {
    int row = blockIdx.x * 8 + (threadIdx.x >> 5);
    int l = threadIdx.x & 31;
    float4 v = ((const float4*)(x + row * NC))[l];
    unsigned p = __builtin_amdgcn_cvt_pk_fp8_f32(v.x, v.y, 0, false);
    p = __builtin_amdgcn_cvt_pk_fp8_f32(v.z, v.w, p, true);
    xq[row * 32 + l] = p;

    float ss = fmaf(v.x, v.x, fmaf(v.y, v.y, fmaf(v.z, v.z, v.w * v.w)));
    float mx = fmaxf(fmaxf(v.x, v.y), fmaxf(v.z, v.w));
#pragma unroll
    for (int off = 16; off; off >>= 1) {
        ss += __shfl_xor(ss, off);
        mx = fmaxf(mx, __shfl_xor(mx, off));
    }
    float es = expf(v.x - mx) + expf(v.y - mx) + expf(v.z - mx) + expf(v.w - mx);
#pragma unroll
    for (int off = 16; off; off >>= 1) es += __shfl_xor(es, off);
    if (l == 0) {
        sq[row] = ss;
        ce[row] = mx + logf(es) - x[row * NC + tgt[row]];
    }
    if (blockIdx.x == 0) {
        uint4 zz = {0u, 0u, 0u, 0u};
#pragma unroll
        for (int k = 0; k < 8; ++k)
            ((uint4*)ctl)[threadIdx.x + k * 256] = zz;
    }
}

// ---------------------------------------------------------------- trip:
// FP8 E4M3 MX-scaled MFMA GEMM. 64x64 j-tiles (JPT=8 per 512-col slice),
// A in regs, B double-buffered (2 x 8 KB) + meta (4 KB) = 20480 B LDS
// -> 8 blocks/CU, 32 waves/CU (the occupancy fix). Proven 1-barrier/jt
// global_load_lds pipeline with XOR-swizzled source. Tail chained fence-free
// (R5 mechanism): 16th j-slice finisher per bx inlines the 64-row hinge+CE,
// 128th bx winner runs Lambert-W.
__global__ __launch_bounds__(256, 8) void k_trip(const unsigned char* __restrict__ xq,
                                                 const int* __restrict__ tgt,
                                                 const float* __restrict__ sq,
                                                 const float* __restrict__ ce,
                                                 unsigned* __restrict__ ctl,
                                                 float* __restrict__ pmax,   // [NSL][NB]
                                                 float* __restrict__ pmin,   // [NSL][NB]
                                                 float* __restrict__ out) {
    __shared__ union {
        struct { unsigned char Bs[2][64 * 128]; float sqs[512]; int tjs[512]; } p2;  // 20480 B
        struct { unsigned doTail; float vmx[4][64]; float vmn[4][64]; } p3;          // 2052 B
    } sm;

    const int tid = threadIdx.x;
    const int lane = tid & 63;
    const int w = tid >> 6;           // wave 0..3
    const int rh = w >> 1;            // row half (32 rows)
    const int ch = w & 1;             // col half (32 cols)
    const int bx = (int)blockIdx.x;   // row block 0..127
    const int by = (int)blockIdx.y;   // j-slice 0..15
    const int i0 = bx * 64;
    const int jbase = by * 512;
    const int m = lane & 15;
    const int quad = lane >> 4;

    // ---- stage j-slice metadata (2 KB sq + 2 KB tgt) ----
    // PROVEN pattern: per-wave uniform LDS base stepping by 256 floats
    // (64 lanes x 16 B); waves 0-1 -> sqs, waves 2-3 -> tjs.
    if (w < 2) {
        __builtin_amdgcn_global_load_lds(
            (const __attribute__((address_space(1))) unsigned*)((const unsigned*)(sq + jbase) + (w * 64 + lane) * 4),
            (__attribute__((address_space(3))) unsigned*)(sm.p2.sqs + w * 256),
            16, 0, 0);
    } else {
        __builtin_amdgcn_global_load_lds(
            (const __attribute__((address_space(1))) unsigned*)((const unsigned*)(tgt + jbase) + ((w - 2) * 64 + lane) * 4),
            (__attribute__((address_space(3))) unsigned*)(sm.p2.tjs + (w - 2) * 256),
            16, 0, 0);
    }

    // ---- stage B tile 0 into buffer 0 (async, XOR-swizzled source) ----
#pragma unroll
    for (int c = 0; c < 2; ++c) {
        int L = w * 128 + c * 64 + lane;          // 16-B chunk 0..511
        int col = L >> 3, cc = L & 7;
        const unsigned char* src = xq + (size_t)(jbase + col) * 128 + ((cc ^ (col & 7)) << 4);
        __builtin_amdgcn_global_load_lds(
            (const __attribute__((address_space(1))) unsigned*)src,
            (__attribute__((address_space(3))) unsigned*)(&sm.p2.Bs[0][0] + (w * 128 + c * 64) * 16),
            16, 0, 0);
    }

    // ---- A fragments straight into registers ----
    v8i a[2];
#pragma unroll
    for (int tm = 0; tm < 2; ++tm) {
        int row = i0 + rh * 32 + tm * 16 + m;
        a[tm] = *(const v8i*)(xq + (size_t)row * 128 + quad * 32);
    }

    // ---- anchor targets ----
    int ti[2][4];
#pragma unroll
    for (int tm = 0; tm < 2; ++tm)
#pragma unroll
        for (int r = 0; r < 4; ++r)
            ti[tm][r] = tgt[i0 + rh * 32 + tm * 16 + quad * 4 + r];

    float mp[2][4], mn[2][4];
#pragma unroll
    for (int tm = 0; tm < 2; ++tm)
#pragma unroll
        for (int r = 0; r < 4; ++r) { mp[tm][r] = -3.0e38f; mn[tm][r] = 3.0e38f; }

#pragma unroll 2
    for (int jt = 0; jt < JPT; ++jt) {
        // drains the prefetch issued last iteration; all waves done with the
        // buffer we're about to overwrite
        __syncthreads();

        // ---- early-issue prefetch of NEXT tile into the other buffer ----
        if (jt + 1 < JPT) {
            int jn = jbase + (jt + 1) * 64;
            unsigned char* Bnxt = &sm.p2.Bs[(jt + 1) & 1][0];
#pragma unroll
            for (int c = 0; c < 2; ++c) {
                int L = w * 128 + c * 64 + lane;
                int col = L >> 3, cc = L & 7;
                const unsigned char* src = xq + (size_t)(jn + col) * 128 + ((cc ^ (col & 7)) << 4);
                __builtin_amdgcn_global_load_lds(
                    (const __attribute__((address_space(1))) unsigned*)src,
                    (__attribute__((address_space(3))) unsigned*)(Bnxt + (w * 128 + c * 64) * 16),
                    16, 0, 0);
            }
        }

        const unsigned char* Bcur = &sm.p2.Bs[jt & 1][0];

        // ---- column metadata from LDS ----
        float sqj[2]; int tj[2];
#pragma unroll
        for (int tn = 0; tn < 2; ++tn) {
            int cloc = jt * 64 + ch * 32 + tn * 16 + m;
            sqj[tn] = sm.p2.sqs[cloc];
            tj[tn] = sm.p2.tjs[cloc];
        }

        // ---- b fragments: two b128 reads per tn (XOR-swizzled) ----
        v8i b[2];
#pragma unroll
        for (int tn = 0; tn < 2; ++tn) {
            int col = ch * 32 + tn * 16 + m;
            int base = col * 128;
            int c0 = (((quad * 2) ^ (col & 7)) << 4);
            int c1 = (((quad * 2 + 1) ^ (col & 7)) << 4);
            *(int4*)&b[tn] = *(const int4*)(Bcur + base + c0);
            *((int4*)&b[tn] + 1) = *(const int4*)(Bcur + base + c1);
        }

        // ---- one MX MFMA per (tm,tn) covers K=128; scales = 1.0 ----
        v4f acc[2][2];
        v4f z = {0.0f, 0.0f, 0.0f, 0.0f};
#pragma unroll
        for (int tm = 0; tm < 2; ++tm)
#pragma unroll
            for (int tn = 0; tn < 2; ++tn)
                acc[tm][tn] = __builtin_amdgcn_mfma_scale_f32_16x16x128_f8f6f4(
                    a[tm], b[tn], z, 0, 0, 0, 0x7f7f7f7f, 0, 0x7f7f7f7f);

        // ---- fused epilogue: v = sqj - 2*dot (sqi added in tail) ----
#pragma unroll
        for (int tn = 0; tn < 2; ++tn) {
#pragma unroll
            for (int tm = 0; tm < 2; ++tm)
#pragma unroll
                for (int r = 0; r < 4; ++r) {
                    float v = fmaf(-2.0f, acc[tm][tn][r], sqj[tn]);
                    bool pos = (tj[tn] == ti[tm][r]);
                    mp[tm][r] = fmaxf(mp[tm][r], pos ? v : -3.0e38f);
                    mn[tm][r] = fminf(mn[tm][r], pos ? 3.0e38f : v);
                }
        }
    }

    // ---- reduce across the 16 lanes sharing each output row ----
#pragma unroll
    for (int off = 1; off < 16; off <<= 1) {
#pragma unroll
        for (int tm = 0; tm < 2; ++tm)
#pragma unroll
            for (int r = 0; r < 4; ++r) {
                mp[tm][r] = fmaxf(mp[tm][r], __shfl_xor(mp[tm][r], off));
                mn[tm][r] = fminf(mn[tm][r], __shfl_xor(mn[tm][r], off));
            }
    }
    // ---- write-through partial stores (small: 1 KB/block) ----
    if (m == 0) {
        int slice = by * 2 + ch;
        float* pm = pmax + (size_t)slice * NB + i0 + rh * 32;
        float* pn = pmin + (size_t)slice * NB + i0 + rh * 32;
#pragma unroll
        for (int tm = 0; tm < 2; ++tm)
#pragma unroll
            for (int r = 0; r < 4; ++r) {
                int rr = tm * 16 + quad * 4 + r;
                st_f32(pm + rr, mp[tm][r]);
                st_f32(pn + rr, mn[tm][r]);
            }
    }

    // ---- last-finisher chaining (fence-free, R5-proven) ----
    __syncthreads();              // drains write-through stores to MALL
    if (tid == 0) {
        unsigned prev = __hip_atomic_fetch_add(ctl + (16u + (unsigned)bx) * 32, 1u,
                                               __ATOMIC_RELAXED, __HIP_MEMORY_SCOPE_AGENT);
        sm.p3.doTail = (prev == (unsigned)(NJS - 1));
    }
    __syncthreads();
    if (!sm.p3.doTail) return;

    // ---------------- chained tail: 32-slice combine, 4 waves ----------------
    {
        int lr = tid & 63, g = tid >> 6;
        int i = i0 + lr;
        float vmax = -3.0e38f, vmin = 3.0e38f;
#pragma unroll
        for (int k = 0; k < 8; ++k) {
            int s = g * 8 + k;
            vmax = fmaxf(vmax, ld_f32(pmax + (size_t)s * NB + i));
            vmin = fminf(vmin, ld_f32(pmin + (size_t)s * NB + i));
        }
        sm.p3.vmx[g][lr] = vmax;
        sm.p3.vmn[g][lr] = vmin;
    }
    __syncthreads();
    if (tid < 64) {
        int i = i0 + tid;
        float vmax = fmaxf(fmaxf(sm.p3.vmx[0][tid], sm.p3.vmx[1][tid]),
                           fmaxf(sm.p3.vmx[2][tid], sm.p3.vmx[3][tid]));
        float vmin = fminf(fminf(sm.p3.vmn[0][tid], sm.p3.vmn[1][tid]),
                           fminf(sm.p3.vmn[2][tid], sm.p3.vmn[3][tid]));
        float sqi = sq[i];
        float ap = sqrtf(fmaxf(fmaxf(sqi + vmax, 0.0f), 1e-12f));
        float an = sqrtf(fmaxf(fmaxf(sqi + vmin, 0.0f), 1e-12f));
        float hs = fmaxf(ap - an + 0.3f, 0.0f);
        float cs = ce[i];
#pragma unroll
        for (int off = 32; off; off >>= 1) {
            hs += __shfl_xor(hs, off);
            cs += __shfl_xor(cs, off);
        }
        if (tid == 0) {
            float* pl = (float*)(ctl + (8u + (unsigned)(bx & 7)) * 32);
            atomicAdd(pl + 0, hs);
            atomicAdd(pl + 1, cs);
            asm volatile("s_waitcnt vmcnt(0)" ::: "memory");   // parts durable before done-RMW
            unsigned prev2 = __hip_atomic_fetch_add(ctl + 0, 1u,
                                                    __ATOMIC_RELAXED, __HIP_MEMORY_SCOPE_AGENT);
            if (prev2 == 127u) {
                double H = 0.0, Cs = 0.0;
#pragma unroll
                for (int k = 0; k < 8; ++k) {
                    float* q = (float*)(ctl + (8u + (unsigned)k) * 32);
                    H  += (double)atomicAdd(q + 0, 0.0f);
                    Cs += (double)atomicAdd(q + 1, 0.0f);
                }
                const double E = 2.71828182845904523536;
                const double TAU = log(128.0);
                const double LAMd = 0.25;
                double l = H / (double)NB;
                double cev = Cs / (double)NB;
                double y = 0.5 * fmax(-2.0 / E, (l - TAU) / LAMd);
                double p = sqrt(fmax(2.0 * (E * y + 1.0), 0.0));
                double wn = -1.0 + p - p * p / 3.0 + (11.0 / 72.0) * p * p * p;
                double wlw = (y < 0.0) ? wn : log1p(fmax(y, 0.0));
#pragma unroll
                for (int it = 0; it < 10; ++it) {
                    double ew = exp(wlw);
                    double f = wlw * ew - y;
                    double wp1 = wlw + 1.0;
                    wlw = wlw - f / (ew * wp1 - (wlw + 2.0) * f / (2.0 * wp1));
                }
                double sigma = exp(-wlw);
                double lg = log(sigma);
                double loss = (cev - TAU) * sigma + LAMd * lg * lg;
                out[0] = (float)(loss / (double)NB);
            }
        }
    }
}

// ---------------------------------------------------------------- launcher
extern "C" void kernel_launch(void* const* d_in, const int* in_sizes, int n_in,
                              void* d_out, int out_size, void* d_ws, size_t ws_size,
                              hipStream_t stream) {
    const float* x = (const float*)d_in[0];
    const int* tgt = (const int*)d_in[1];
    float* out = (float*)d_out;

    // ws: xq (1 MB) | sq (32 KB) | ce (32 KB) | ctl (32 KB) | pmax (1 MB) | pmin (1 MB)
    unsigned char* xq = (unsigned char*)d_ws;
    float* sq = (float*)(xq + (size_t)NB * 128);
    float* ce = sq + NB;
    unsigned* ctl = (unsigned*)(ce + NB);
    float* pmax = (float*)((unsigned char*)ctl + 32768);
    float* pmin = pmax + (size_t)NSL * NB;

    k_prep<<<NB / 8, 256, 0, stream>>>(x, tgt, (unsigned*)xq, sq, ce, ctl);
    dim3 grid(NB / 64, NJS);
    k_trip<<<grid, 256, 0, stream>>>(xq, tgt, sq, ce, ctl, pmax, pmin, out);
}